// Round 1
// baseline (7160.925 us; speedup 1.0000x reference)
//
#include <hip/hip_runtime.h>
#include <hip/hip_bf16.h>

using short8 = __attribute__((ext_vector_type(8))) short;
using f32x4  = __attribute__((ext_vector_type(4))) float;

static constexpr int NN = 65536;   // nodes
static constexpr int F  = 256;     // feature dim
static constexpr int KE = 8;       // experts
static constexpr int KD = KE * F;  // 2048 = GEMM inner dim

__device__ __forceinline__ short f2bf(float f) {
    union { __hip_bfloat16 h; short s; } u;
    u.h = __float2bfloat16(f);
    return u.s;
}

// ---------- Phase 0: W [8][256][256] f32 -> WbT [256][2048] bf16, WbT[o][e*256+i] = W[e][i][o]
__global__ void prep_w(const float* __restrict__ W, short* __restrict__ WbT) {
    __shared__ float tile[64][65];  // +1 pad: conflict-free transpose
    const int e  = blockIdx.z;
    const int i0 = blockIdx.x * 64;
    const int o0 = blockIdx.y * 64;
    const int c  = threadIdx.x & 63;
    const int r4 = threadIdx.x >> 6;
    for (int rr = r4; rr < 64; rr += 4)
        tile[rr][c] = W[((size_t)e * F + i0 + rr) * F + o0 + c];
    __syncthreads();
    for (int rr = r4; rr < 64; rr += 4)
        WbT[(size_t)(o0 + rr) * KD + e * F + i0 + c] = f2bf(tile[c][rr]);
}

// ---------- Phase 1: hi[rows[e]] += vals[e] * x[cols[e]]  (atomic scatter, 1 wave/edge)
__global__ void spmm_atomic(const float* __restrict__ x, const float* __restrict__ vals,
                            const int* __restrict__ rows, const int* __restrict__ cols,
                            float* __restrict__ hi, int E) {
    const long long gwv = ((long long)blockIdx.x * blockDim.x + threadIdx.x) >> 6;
    if (gwv >= E) return;
    const int wv = (int)gwv;
    const int lane = threadIdx.x & 63;
    const int r  = rows[wv];
    const int cl = cols[wv];
    const float v = vals[wv];
    const float4 xa = ((const float4*)(x + (size_t)cl * F))[lane];
    float* hp = hi + (size_t)r * F + lane * 4;
    atomicAdd(hp + 0, v * xa.x);
    atomicAdd(hp + 1, v * xa.y);
    atomicAdd(hp + 2, v * xa.z);
    atomicAdd(hp + 3, v * xa.w);
}

// ---------- Phase 2: out[n,o] = sum_e z[n,e] * (hi[n,:] @ W[e]) + x[n,o]
// BM=128 rows/block, full 256 cols. 8 waves in 2x4: each wave 64x64 (4x4 16x16 frags).
// Expert-outer loop; z folded into accumulator at expert boundaries (64 FMA/wave/expert)
// so the inner loop is pure ds_read_b128 + MFMA.
#define BM 128
__global__ __launch_bounds__(512, 1)
void moe_gemm(const float* __restrict__ hi, const float* __restrict__ z,
              const short* __restrict__ WbT, const float* __restrict__ x,
              float* __restrict__ out) {
    __shared__ short hi_lds[BM * F];   // 64 KiB, XOR-swizzled bf16
    __shared__ float z_lds[BM * KE];   // 4 KiB
    const int tid  = threadIdx.x;
    const int lane = tid & 63;
    const int w    = tid >> 6;
    const int wr   = w >> 2;           // 0..1 : row half
    const int wc   = w & 3;            // 0..3 : col quarter
    const int row0 = blockIdx.x * BM;

    // stage z [128][8]
    for (int idx = tid; idx < BM * KE; idx += 512)
        z_lds[idx] = z[(size_t)row0 * KE + idx];

    // stage hi -> bf16 LDS with XOR swizzle (row-major [128][256] @512B stride
    // would be a 16-way bank conflict on ds_read_b128 otherwise)
    {
        const int mrow = tid >> 5;     // 16 rows per pass
        const int c8   = tid & 31;     // 8-float chunk
        for (int p = 0; p < BM / 16; ++p) {
            const int m = p * 16 + mrow;
            const float4* src = (const float4*)(hi + (size_t)(row0 + m) * F + c8 * 8);
            const float4 a = src[0], b = src[1];
            short8 pk;
            pk[0]=f2bf(a.x); pk[1]=f2bf(a.y); pk[2]=f2bf(a.z); pk[3]=f2bf(a.w);
            pk[4]=f2bf(b.x); pk[5]=f2bf(b.y); pk[6]=f2bf(b.z); pk[7]=f2bf(b.w);
            const int idx = (m * F + c8 * 8) ^ ((m & 7) << 3);
            *(short8*)&hi_lds[idx] = pk;
        }
    }
    __syncthreads();

    f32x4 acc_t[4][4];
    #pragma unroll
    for (int mi = 0; mi < 4; ++mi)
        #pragma unroll
        for (int ni = 0; ni < 4; ++ni)
            acc_t[mi][ni] = (f32x4){0.f, 0.f, 0.f, 0.f};

    const int krow  = 8 * (lane >> 4);
    const int lr    = lane & 15;
    const int rbase = (lane >> 4) * 4;

    for (int e = 0; e < KE; ++e) {
        f32x4 acc_e[4][4];
        #pragma unroll
        for (int mi = 0; mi < 4; ++mi)
            #pragma unroll
            for (int ni = 0; ni < 4; ++ni)
                acc_e[mi][ni] = (f32x4){0.f, 0.f, 0.f, 0.f};

        #pragma unroll
        for (int i0 = 0; i0 < F; i0 += 32) {
            short8 af[4], bf[4];
            #pragma unroll
            for (int mi = 0; mi < 4; ++mi) {
                const int m = wr * 64 + mi * 16 + lr;
                af[mi] = *(const short8*)&hi_lds[(m * F + i0 + krow) ^ ((m & 7) << 3)];
            }
            #pragma unroll
            for (int ni = 0; ni < 4; ++ni) {
                const int o = wc * 64 + ni * 16 + lr;
                bf[ni] = *(const short8*)&WbT[(size_t)o * KD + e * F + i0 + krow];
            }
            #pragma unroll
            for (int mi = 0; mi < 4; ++mi)
                #pragma unroll
                for (int ni = 0; ni < 4; ++ni)
                    acc_e[mi][ni] = __builtin_amdgcn_mfma_f32_16x16x32_bf16(
                        af[mi], bf[ni], acc_e[mi][ni], 0, 0, 0);
        }

        // fold z[m][e] into running accumulator (C/D layout: row=(lane>>4)*4+r, col=lane&15)
        #pragma unroll
        for (int mi = 0; mi < 4; ++mi) {
            float zv[4];
            #pragma unroll
            for (int r = 0; r < 4; ++r)
                zv[r] = z_lds[(wr * 64 + mi * 16 + rbase + r) * KE + e];
            #pragma unroll
            for (int ni = 0; ni < 4; ++ni)
                #pragma unroll
                for (int r = 0; r < 4; ++r)
                    acc_t[mi][ni][r] += zv[r] * acc_e[mi][ni][r];
        }
    }

    // epilogue: residual + store
    #pragma unroll
    for (int mi = 0; mi < 4; ++mi) {
        #pragma unroll
        for (int ni = 0; ni < 4; ++ni) {
            const int o = wc * 64 + ni * 16 + lr;
            #pragma unroll
            for (int r = 0; r < 4; ++r) {
                const int m = wr * 64 + mi * 16 + rbase + r;
                const size_t off = (size_t)(row0 + m) * F + o;
                out[off] = acc_t[mi][ni][r] + x[off];
            }
        }
    }
}

extern "C" void kernel_launch(void* const* d_in, const int* in_sizes, int n_in,
                              void* d_out, int out_size, void* d_ws, size_t ws_size,
                              hipStream_t stream) {
    const float* x    = (const float*)d_in[0];
    // d_in[1] = h0 : unused by the reference (variant=False path)
    const float* z    = (const float*)d_in[2];
    const float* vals = (const float*)d_in[3];
    const float* W    = (const float*)d_in[4];
    const int* rows   = (const int*)d_in[5];
    const int* cols   = (const int*)d_in[6];
    float* out        = (float*)d_out;
    const int E = in_sizes[3];

    // workspace layout: hi f32 [NN*F] (64 MB) | WbT bf16 [F*KD] (1 MB)
    float* hi  = (float*)d_ws;
    short* WbT = (short*)((char*)d_ws + (size_t)NN * F * sizeof(float));

    hipMemsetAsync(d_ws, 0, (size_t)NN * F * sizeof(float), stream);
    prep_w<<<dim3(4, 4, 8), 256, 0, stream>>>(W, WbT);
    spmm_atomic<<<(E + 3) / 4, 256, 0, stream>>>(x, vals, rows, cols, hi, E);
    moe_gemm<<<NN / BM, 512, 0, stream>>>(hi, z, WbT, x, out);
}

// Round 2
// 794.211 us; speedup vs baseline: 9.0164x; 9.0164x over previous
//
#include <hip/hip_runtime.h>
#include <hip/hip_bf16.h>

using short8 = __attribute__((ext_vector_type(8))) short;
using f32x4  = __attribute__((ext_vector_type(4))) float;

static constexpr int NN = 65536;   // nodes
static constexpr int F  = 256;     // feature dim
static constexpr int KE = 8;       // experts
static constexpr int KD = KE * F;  // 2048 = GEMM inner dim

__device__ __forceinline__ short f2bf(float f) {
    union { __hip_bfloat16 h; short s; } u;
    u.h = __float2bfloat16(f);
    return u.s;
}

// ---------- Phase 0: W [8][256][256] f32 -> WbT [256][2048] bf16, WbT[o][e*256+i] = W[e][i][o]
__global__ void prep_w(const float* __restrict__ W, short* __restrict__ WbT) {
    __shared__ float tile[64][65];
    const int e  = blockIdx.z;
    const int i0 = blockIdx.x * 64;
    const int o0 = blockIdx.y * 64;
    const int c  = threadIdx.x & 63;
    const int r4 = threadIdx.x >> 6;
    for (int rr = r4; rr < 64; rr += 4)
        tile[rr][c] = W[((size_t)e * F + i0 + rr) * F + o0 + c];
    __syncthreads();
    for (int rr = r4; rr < 64; rr += 4)
        WbT[(size_t)(o0 + rr) * KD + e * F + i0 + c] = f2bf(tile[c][rr]);
}

// ---------- Phase 1a: histogram of destination rows
__global__ void hist_rows(const int* __restrict__ rows, int* __restrict__ counts, int E) {
    const int e = blockIdx.x * blockDim.x + threadIdx.x;
    if (e < E) atomicAdd(&counts[rows[e]], 1);
}

// ---------- Phase 1b: exclusive scan over 65536 counts (single block)
__global__ __launch_bounds__(1024)
void scan_counts(const int* __restrict__ counts, int* __restrict__ offsets,
                 int* __restrict__ cursor) {
    __shared__ int sums[1024];
    const int t = threadIdx.x;
    const int base = t * 64;
    int s = 0;
    for (int i = 0; i < 64; ++i) s += counts[base + i];
    sums[t] = s;
    __syncthreads();
    for (int off = 1; off < 1024; off <<= 1) {
        int v = (t >= off) ? sums[t - off] : 0;
        __syncthreads();
        sums[t] += v;
        __syncthreads();
    }
    int run = (t == 0) ? 0 : sums[t - 1];
    for (int i = 0; i < 64; ++i) {
        const int c = counts[base + i];
        offsets[base + i] = run;
        cursor[base + i]  = run;
        run += c;
    }
    if (t == 1023) offsets[NN] = run;
}

// ---------- Phase 1c: scatter edges into row-sorted (col, val) pairs
__global__ void scatter_edges(const int* __restrict__ rows, const int* __restrict__ cols,
                              const float* __restrict__ vals, int* __restrict__ cursor,
                              int2* __restrict__ scv, int E) {
    const int e = blockIdx.x * blockDim.x + threadIdx.x;
    if (e >= E) return;
    const int r = rows[e];
    const int p = atomicAdd(&cursor[r], 1);
    scv[p] = make_int2(cols[e], __float_as_int(vals[e]));
}

// ---------- Phase 1d: per-row segmented gather-accumulate, hi written as bf16
__global__ __launch_bounds__(256)
void gather_rows(const float* __restrict__ x, const int2* __restrict__ scv,
                 const int* __restrict__ offsets, short* __restrict__ hi) {
    const int lane = threadIdx.x & 63;
    int row = (blockIdx.x << 2) + (threadIdx.x >> 6);
    row = __builtin_amdgcn_readfirstlane(row);
    const int beg = offsets[row];
    const int end = offsets[row + 1];
    float4 acc = {0.f, 0.f, 0.f, 0.f};
    int j = beg;
    for (; j + 4 <= end; j += 4) {
        const int2 c0 = scv[j+0], c1 = scv[j+1], c2 = scv[j+2], c3 = scv[j+3];
        const float4 x0 = ((const float4*)(x + (size_t)c0.x * F))[lane];
        const float4 x1 = ((const float4*)(x + (size_t)c1.x * F))[lane];
        const float4 x2 = ((const float4*)(x + (size_t)c2.x * F))[lane];
        const float4 x3 = ((const float4*)(x + (size_t)c3.x * F))[lane];
        const float v0 = __int_as_float(c0.y), v1 = __int_as_float(c1.y);
        const float v2 = __int_as_float(c2.y), v3 = __int_as_float(c3.y);
        acc.x += v0*x0.x + v1*x1.x + v2*x2.x + v3*x3.x;
        acc.y += v0*x0.y + v1*x1.y + v2*x2.y + v3*x3.y;
        acc.z += v0*x0.z + v1*x1.z + v2*x2.z + v3*x3.z;
        acc.w += v0*x0.w + v1*x1.w + v2*x2.w + v3*x3.w;
    }
    for (; j < end; ++j) {
        const int2 c0 = scv[j];
        const float4 x0 = ((const float4*)(x + (size_t)c0.x * F))[lane];
        const float v0 = __int_as_float(c0.y);
        acc.x += v0*x0.x; acc.y += v0*x0.y; acc.z += v0*x0.z; acc.w += v0*x0.w;
    }
    union { short s[4]; int2 i2; } o;
    o.s[0] = f2bf(acc.x); o.s[1] = f2bf(acc.y);
    o.s[2] = f2bf(acc.z); o.s[3] = f2bf(acc.w);
    ((int2*)(hi + (size_t)row * F))[lane] = o.i2;
}

// ---------- Phase 2: out[n,o] = sum_e z[n,e] * (hi[n,:] @ W[e]) + x[n,o]
#define BM 128
__global__ __launch_bounds__(512, 1)
void moe_gemm(const short* __restrict__ hi, const float* __restrict__ z,
              const short* __restrict__ WbT, const float* __restrict__ x,
              float* __restrict__ out) {
    __shared__ short hi_lds[BM * F];   // 64 KiB, XOR-swizzled bf16
    __shared__ float z_lds[BM * KE];   // 4 KiB
    const int tid  = threadIdx.x;
    const int lane = tid & 63;
    const int w    = tid >> 6;
    const int wr   = w >> 2;
    const int wc   = w & 3;
    const int row0 = blockIdx.x * BM;

    for (int idx = tid; idx < BM * KE; idx += 512)
        z_lds[idx] = z[(size_t)row0 * KE + idx];

    // stage hi (bf16) -> LDS with XOR swizzle
    {
        const int m0  = tid >> 5;      // 16 rows per pass
        const int c16 = tid & 31;      // 16B chunk within row
        for (int p = 0; p < BM / 16; ++p) {
            const int m = p * 16 + m0;
            const short8 v = *(const short8*)(hi + (size_t)(row0 + m) * F + c16 * 8);
            const int idx = (m * F + c16 * 8) ^ ((m & 7) << 3);
            *(short8*)&hi_lds[idx] = v;
        }
    }
    __syncthreads();

    f32x4 acc_t[4][4];
    #pragma unroll
    for (int mi = 0; mi < 4; ++mi)
        #pragma unroll
        for (int ni = 0; ni < 4; ++ni)
            acc_t[mi][ni] = (f32x4){0.f, 0.f, 0.f, 0.f};

    const int krow  = 8 * (lane >> 4);
    const int lr    = lane & 15;
    const int rbase = (lane >> 4) * 4;

    for (int e = 0; e < KE; ++e) {
        f32x4 acc_e[4][4];
        #pragma unroll
        for (int mi = 0; mi < 4; ++mi)
            #pragma unroll
            for (int ni = 0; ni < 4; ++ni)
                acc_e[mi][ni] = (f32x4){0.f, 0.f, 0.f, 0.f};

        #pragma unroll
        for (int i0 = 0; i0 < F; i0 += 32) {
            short8 af[4], bf[4];
            #pragma unroll
            for (int mi = 0; mi < 4; ++mi) {
                const int m = wr * 64 + mi * 16 + lr;
                af[mi] = *(const short8*)&hi_lds[(m * F + i0 + krow) ^ ((m & 7) << 3)];
            }
            #pragma unroll
            for (int ni = 0; ni < 4; ++ni) {
                const int o = wc * 64 + ni * 16 + lr;
                bf[ni] = *(const short8*)&WbT[(size_t)o * KD + e * F + i0 + krow];
            }
            #pragma unroll
            for (int mi = 0; mi < 4; ++mi)
                #pragma unroll
                for (int ni = 0; ni < 4; ++ni)
                    acc_e[mi][ni] = __builtin_amdgcn_mfma_f32_16x16x32_bf16(
                        af[mi], bf[ni], acc_e[mi][ni], 0, 0, 0);
        }

        #pragma unroll
        for (int mi = 0; mi < 4; ++mi) {
            float zv[4];
            #pragma unroll
            for (int r = 0; r < 4; ++r)
                zv[r] = z_lds[(wr * 64 + mi * 16 + rbase + r) * KE + e];
            #pragma unroll
            for (int ni = 0; ni < 4; ++ni)
                #pragma unroll
                for (int r = 0; r < 4; ++r)
                    acc_t[mi][ni][r] += zv[r] * acc_e[mi][ni][r];
        }
    }

    #pragma unroll
    for (int mi = 0; mi < 4; ++mi) {
        #pragma unroll
        for (int ni = 0; ni < 4; ++ni) {
            const int o = wc * 64 + ni * 16 + lr;
            #pragma unroll
            for (int r = 0; r < 4; ++r) {
                const int m = wr * 64 + mi * 16 + rbase + r;
                const size_t off = (size_t)(row0 + m) * F + o;
                out[off] = acc_t[mi][ni][r] + x[off];
            }
        }
    }
}

extern "C" void kernel_launch(void* const* d_in, const int* in_sizes, int n_in,
                              void* d_out, int out_size, void* d_ws, size_t ws_size,
                              hipStream_t stream) {
    const float* x    = (const float*)d_in[0];
    // d_in[1] = h0 : unused by the reference (variant=False path)
    const float* z    = (const float*)d_in[2];
    const float* vals = (const float*)d_in[3];
    const float* W    = (const float*)d_in[4];
    const int* rows   = (const int*)d_in[5];
    const int* cols   = (const int*)d_in[6];
    float* out        = (float*)d_out;
    const int E = in_sizes[3];

    // workspace layout
    char* ws = (char*)d_ws;
    short* hi     = (short*)(ws);                                   // 32 MB bf16 [NN][F]
    short* WbT    = (short*)(ws + ((size_t)32 << 20));              // 1 MB
    int*   counts = (int*)  (ws + ((size_t)33 << 20));              // 256 KB
    int*   offs   = (int*)  (ws + ((size_t)33 << 20) + (256 << 10));          // 256KB+64
    int*   cursor = (int*)  (ws + ((size_t)33 << 20) + 2*(256 << 10) + 64);   // 256 KB
    int2*  scv    = (int2*) (ws + ((size_t)33 << 20) + 3*(256 << 10) + 128);  // 16 MB

    hipMemsetAsync(counts, 0, (size_t)NN * sizeof(int), stream);
    prep_w<<<dim3(4, 4, 8), 256, 0, stream>>>(W, WbT);
    hist_rows<<<(E + 255) / 256, 256, 0, stream>>>(rows, counts, E);
    scan_counts<<<1, 1024, 0, stream>>>(counts, offs, cursor);
    scatter_edges<<<(E + 255) / 256, 256, 0, stream>>>(rows, cols, vals, cursor, scv, E);
    gather_rows<<<NN / 4, 256, 0, stream>>>(x, scv, offs, hi);
    moe_gemm<<<NN / BM, 512, 0, stream>>>(hi, z, WbT, x, out);
}

// Round 3
// 675.146 us; speedup vs baseline: 10.6065x; 1.1764x over previous
//
#include <hip/hip_runtime.h>
#include <hip/hip_bf16.h>

using short8 = __attribute__((ext_vector_type(8))) short;
using f32x4  = __attribute__((ext_vector_type(4))) float;

static constexpr int NN = 65536;   // nodes
static constexpr int F  = 256;     // feature dim
static constexpr int KE = 8;       // experts
static constexpr int KD = KE * F;  // 2048 = GEMM inner dim

__device__ __forceinline__ short f2bf(float f) {
    union { __hip_bfloat16 h; short s; } u;
    u.h = __float2bfloat16(f);
    return u.s;
}
__device__ __forceinline__ float bf_lo(unsigned u) { return __uint_as_float(u << 16); }
__device__ __forceinline__ float bf_hi(unsigned u) { return __uint_as_float(u & 0xFFFF0000u); }

// ---------- Phase -1: x f32 -> xb bf16 (halves gather read traffic)
__global__ __launch_bounds__(256)
void conv_x(const float* __restrict__ x, short* __restrict__ xb) {
    const size_t i = ((size_t)blockIdx.x * 256 + threadIdx.x) * 8;
    const float4 a = *(const float4*)(x + i);
    const float4 b = *(const float4*)(x + i + 4);
    short8 p;
    p[0]=f2bf(a.x); p[1]=f2bf(a.y); p[2]=f2bf(a.z); p[3]=f2bf(a.w);
    p[4]=f2bf(b.x); p[5]=f2bf(b.y); p[6]=f2bf(b.z); p[7]=f2bf(b.w);
    *(short8*)(xb + i) = p;
}

// ---------- Phase 0: W [8][256][256] f32 -> WbT [256][2048] bf16, WbT[o][e*256+i] = W[e][i][o]
__global__ void prep_w(const float* __restrict__ W, short* __restrict__ WbT) {
    __shared__ float tile[64][65];
    const int e  = blockIdx.z;
    const int i0 = blockIdx.x * 64;
    const int o0 = blockIdx.y * 64;
    const int c  = threadIdx.x & 63;
    const int r4 = threadIdx.x >> 6;
    for (int rr = r4; rr < 64; rr += 4)
        tile[rr][c] = W[((size_t)e * F + i0 + rr) * F + o0 + c];
    __syncthreads();
    for (int rr = r4; rr < 64; rr += 4)
        WbT[(size_t)(o0 + rr) * KD + e * F + i0 + c] = f2bf(tile[c][rr]);
}

// ---------- Phase 1a: histogram of destination rows
__global__ void hist_rows(const int* __restrict__ rows, int* __restrict__ counts, int E) {
    const int e = blockIdx.x * blockDim.x + threadIdx.x;
    if (e < E) atomicAdd(&counts[rows[e]], 1);
}

// ---------- Phase 1b: exclusive scan over 65536 counts (single block)
__global__ __launch_bounds__(1024)
void scan_counts(const int* __restrict__ counts, int* __restrict__ offsets,
                 int* __restrict__ cursor) {
    __shared__ int sums[1024];
    const int t = threadIdx.x;
    const int base = t * 64;
    int s = 0;
    for (int i = 0; i < 64; ++i) s += counts[base + i];
    sums[t] = s;
    __syncthreads();
    for (int off = 1; off < 1024; off <<= 1) {
        int v = (t >= off) ? sums[t - off] : 0;
        __syncthreads();
        sums[t] += v;
        __syncthreads();
    }
    int run = (t == 0) ? 0 : sums[t - 1];
    for (int i = 0; i < 64; ++i) {
        const int c = counts[base + i];
        offsets[base + i] = run;
        cursor[base + i]  = run;
        run += c;
    }
    if (t == 1023) offsets[NN] = run;
}

// ---------- Phase 1c: scatter edges into row-sorted (col, val) pairs
__global__ void scatter_edges(const int* __restrict__ rows, const int* __restrict__ cols,
                              const float* __restrict__ vals, int* __restrict__ cursor,
                              int2* __restrict__ scv, int E) {
    const int e = blockIdx.x * blockDim.x + threadIdx.x;
    if (e >= E) return;
    const int r = rows[e];
    const int p = atomicAdd(&cursor[r], 1);
    scv[p] = make_int2(cols[e], __float_as_int(vals[e]));
}

// ---------- Phase 1d: per-row segmented gather (bf16 x), hi written f32 into d_out
__global__ __launch_bounds__(256)
void gather_rows(const short* __restrict__ xb, const int2* __restrict__ scv,
                 const int* __restrict__ offsets, float* __restrict__ hi) {
    const int lane = threadIdx.x & 63;
    int row = (blockIdx.x << 2) + (threadIdx.x >> 6);
    row = __builtin_amdgcn_readfirstlane(row);
    const int beg = offsets[row];
    const int end = offsets[row + 1];
    float4 acc = {0.f, 0.f, 0.f, 0.f};
    int j = beg;
    for (; j + 4 <= end; j += 4) {
        const int2 c0 = scv[j+0], c1 = scv[j+1], c2 = scv[j+2], c3 = scv[j+3];
        const int2 r0 = ((const int2*)(xb + (size_t)c0.x * F))[lane];
        const int2 r1 = ((const int2*)(xb + (size_t)c1.x * F))[lane];
        const int2 r2 = ((const int2*)(xb + (size_t)c2.x * F))[lane];
        const int2 r3 = ((const int2*)(xb + (size_t)c3.x * F))[lane];
        const float v0 = __int_as_float(c0.y), v1 = __int_as_float(c1.y);
        const float v2 = __int_as_float(c2.y), v3 = __int_as_float(c3.y);
        acc.x += v0*bf_lo(r0.x) + v1*bf_lo(r1.x) + v2*bf_lo(r2.x) + v3*bf_lo(r3.x);
        acc.y += v0*bf_hi(r0.x) + v1*bf_hi(r1.x) + v2*bf_hi(r2.x) + v3*bf_hi(r3.x);
        acc.z += v0*bf_lo(r0.y) + v1*bf_lo(r1.y) + v2*bf_lo(r2.y) + v3*bf_lo(r3.y);
        acc.w += v0*bf_hi(r0.y) + v1*bf_hi(r1.y) + v2*bf_hi(r2.y) + v3*bf_hi(r3.y);
    }
    for (; j < end; ++j) {
        const int2 c0 = scv[j];
        const int2 r0 = ((const int2*)(xb + (size_t)c0.x * F))[lane];
        const float v0 = __int_as_float(c0.y);
        acc.x += v0*bf_lo(r0.x); acc.y += v0*bf_hi(r0.x);
        acc.z += v0*bf_lo(r0.y); acc.w += v0*bf_hi(r0.y);
    }
    ((float4*)(hi + (size_t)row * F))[lane] = acc;
}

// ---------- Phase 2: out[n,o] = sum_e z[n,e] * (hi[n,:] @ W[e]) + x[n,o]
// hi lives IN d_out (f32); each block reads only its own 128 rows before
// overwriting them (staged to LDS pre-barrier), so in-place is race-free.
#define BM 128
__global__ __launch_bounds__(512, 1)
void moe_gemm(const float* __restrict__ hi, const float* __restrict__ z,
              const short* __restrict__ WbT, const float* __restrict__ x,
              float* __restrict__ out) {
    __shared__ short hi_lds[BM * F];   // 64 KiB, XOR-swizzled bf16
    __shared__ float z_lds[BM * KE];   // 4 KiB
    const int tid  = threadIdx.x;
    const int lane = tid & 63;
    const int w    = tid >> 6;
    const int wr   = w >> 2;
    const int wc   = w & 3;
    const int row0 = blockIdx.x * BM;

    for (int idx = tid; idx < BM * KE; idx += 512)
        z_lds[idx] = z[(size_t)row0 * KE + idx];

    // stage hi (f32 in d_out) -> bf16 LDS with XOR swizzle
    {
        const int m0 = tid >> 5;       // 16 rows per pass
        const int c8 = tid & 31;       // 8-float chunk
        for (int p = 0; p < BM / 16; ++p) {
            const int m = p * 16 + m0;
            const float4* src = (const float4*)(hi + (size_t)(row0 + m) * F + c8 * 8);
            const float4 a = src[0], b = src[1];
            short8 pk;
            pk[0]=f2bf(a.x); pk[1]=f2bf(a.y); pk[2]=f2bf(a.z); pk[3]=f2bf(a.w);
            pk[4]=f2bf(b.x); pk[5]=f2bf(b.y); pk[6]=f2bf(b.z); pk[7]=f2bf(b.w);
            const int idx = (m * F + c8 * 8) ^ ((m & 7) << 3);
            *(short8*)&hi_lds[idx] = pk;
        }
    }
    __syncthreads();

    f32x4 acc_t[4][4];
    #pragma unroll
    for (int mi = 0; mi < 4; ++mi)
        #pragma unroll
        for (int ni = 0; ni < 4; ++ni)
            acc_t[mi][ni] = (f32x4){0.f, 0.f, 0.f, 0.f};

    const int krow  = 8 * (lane >> 4);
    const int lr    = lane & 15;
    const int rbase = (lane >> 4) * 4;

    for (int e = 0; e < KE; ++e) {
        f32x4 acc_e[4][4];
        #pragma unroll
        for (int mi = 0; mi < 4; ++mi)
            #pragma unroll
            for (int ni = 0; ni < 4; ++ni)
                acc_e[mi][ni] = (f32x4){0.f, 0.f, 0.f, 0.f};

        #pragma unroll
        for (int i0 = 0; i0 < F; i0 += 32) {
            short8 af[4], bf[4];
            #pragma unroll
            for (int mi = 0; mi < 4; ++mi) {
                const int m = wr * 64 + mi * 16 + lr;
                af[mi] = *(const short8*)&hi_lds[(m * F + i0 + krow) ^ ((m & 7) << 3)];
            }
            #pragma unroll
            for (int ni = 0; ni < 4; ++ni) {
                const int o = wc * 64 + ni * 16 + lr;
                bf[ni] = *(const short8*)&WbT[(size_t)o * KD + e * F + i0 + krow];
            }
            #pragma unroll
            for (int mi = 0; mi < 4; ++mi)
                #pragma unroll
                for (int ni = 0; ni < 4; ++ni)
                    acc_e[mi][ni] = __builtin_amdgcn_mfma_f32_16x16x32_bf16(
                        af[mi], bf[ni], acc_e[mi][ni], 0, 0, 0);
        }

        #pragma unroll
        for (int mi = 0; mi < 4; ++mi) {
            float zv[4];
            #pragma unroll
            for (int r = 0; r < 4; ++r)
                zv[r] = z_lds[(wr * 64 + mi * 16 + rbase + r) * KE + e];
            #pragma unroll
            for (int ni = 0; ni < 4; ++ni)
                #pragma unroll
                for (int r = 0; r < 4; ++r)
                    acc_t[mi][ni][r] += zv[r] * acc_e[mi][ni][r];
        }
    }

    #pragma unroll
    for (int mi = 0; mi < 4; ++mi) {
        #pragma unroll
        for (int ni = 0; ni < 4; ++ni) {
            const int o = wc * 64 + ni * 16 + lr;
            #pragma unroll
            for (int r = 0; r < 4; ++r) {
                const int m = wr * 64 + mi * 16 + rbase + r;
                const size_t off = (size_t)(row0 + m) * F + o;
                out[off] = acc_t[mi][ni][r] + x[off];
            }
        }
    }
}

extern "C" void kernel_launch(void* const* d_in, const int* in_sizes, int n_in,
                              void* d_out, int out_size, void* d_ws, size_t ws_size,
                              hipStream_t stream) {
    const float* x    = (const float*)d_in[0];
    // d_in[1] = h0 : unused by the reference (variant=False path)
    const float* z    = (const float*)d_in[2];
    const float* vals = (const float*)d_in[3];
    const float* W    = (const float*)d_in[4];
    const int* rows   = (const int*)d_in[5];
    const int* cols   = (const int*)d_in[6];
    float* out        = (float*)d_out;
    const int E = in_sizes[3];

    // workspace layout (~50 MB total)
    char* ws = (char*)d_ws;
    short* xb     = (short*)(ws);                                   // 32 MB bf16 [NN][F]
    short* WbT    = (short*)(ws + ((size_t)32 << 20));              // 1 MB
    int*   counts = (int*)  (ws + ((size_t)33 << 20));              // 256 KB
    int*   offs   = (int*)  (ws + ((size_t)33 << 20) + (256 << 10));          // 256KB+64
    int*   cursor = (int*)  (ws + ((size_t)33 << 20) + 2*(256 << 10) + 64);   // 256 KB
    int2*  scv    = (int2*) (ws + ((size_t)33 << 20) + 3*(256 << 10) + 128);  // 16 MB
    float* hi     = out;   // gather output lives in d_out; moe_gemm is in-place

    hipMemsetAsync(counts, 0, (size_t)NN * sizeof(int), stream);
    conv_x<<<(NN * F) / (256 * 8), 256, 0, stream>>>(x, xb);
    prep_w<<<dim3(4, 4, 8), 256, 0, stream>>>(W, WbT);
    hist_rows<<<(E + 255) / 256, 256, 0, stream>>>(rows, counts, E);
    scan_counts<<<1, 1024, 0, stream>>>(counts, offs, cursor);
    scatter_edges<<<(E + 255) / 256, 256, 0, stream>>>(rows, cols, vals, cursor, scv, E);
    gather_rows<<<NN / 4, 256, 0, stream>>>(xb, scv, offs, hi);
    moe_gemm<<<NN / BM, 512, 0, stream>>>(hi, z, WbT, x, out);
}

// Round 4
// 553.889 us; speedup vs baseline: 12.9285x; 1.2189x over previous
//
#include <hip/hip_runtime.h>
#include <hip/hip_bf16.h>

using short8 = __attribute__((ext_vector_type(8))) short;
using f32x4  = __attribute__((ext_vector_type(4))) float;
typedef unsigned int u32;

static constexpr int NN = 65536;   // nodes
static constexpr int F  = 256;     // feat dim
static constexpr int KE = 8;       // experts
static constexpr int KD = KE * F;  // 2048 = GEMM inner dim

__device__ __forceinline__ short f2bf(float f) {
    union { __hip_bfloat16 h; short s; } u;
    u.h = __float2bfloat16(f);
    return u.s;
}
__device__ __forceinline__ float bf_lo(unsigned u) { return __uint_as_float(u << 16); }
__device__ __forceinline__ float bf_hi(unsigned u) { return __uint_as_float(u & 0xFFFF0000u); }

// async 16B global->LDS (dest = wave-uniform base + lane*16, HW-enforced)
__device__ __forceinline__ void gld_lds16(void* lds, const void* g) {
    __builtin_amdgcn_global_load_lds((const __attribute__((address_space(1))) u32*)g,
                                     (__attribute__((address_space(3))) u32*)lds, 16, 0, 0);
}

// ---------- Phase -1: x f32 -> xb bf16 (halves gather read traffic)
__global__ __launch_bounds__(256)
void conv_x(const float* __restrict__ x, short* __restrict__ xb) {
    const size_t i = ((size_t)blockIdx.x * 256 + threadIdx.x) * 8;
    const float4 a = *(const float4*)(x + i);
    const float4 b = *(const float4*)(x + i + 4);
    short8 p;
    p[0]=f2bf(a.x); p[1]=f2bf(a.y); p[2]=f2bf(a.z); p[3]=f2bf(a.w);
    p[4]=f2bf(b.x); p[5]=f2bf(b.y); p[6]=f2bf(b.z); p[7]=f2bf(b.w);
    *(short8*)(xb + i) = p;
}

// ---------- Phase 0: W [8][256][256] f32 -> WbT [256][2048] bf16, WbT[o][e*256+i] = W[e][i][o]
__global__ void prep_w(const float* __restrict__ W, short* __restrict__ WbT) {
    __shared__ float tile[64][65];
    const int e  = blockIdx.z;
    const int i0 = blockIdx.x * 64;
    const int o0 = blockIdx.y * 64;
    const int c  = threadIdx.x & 63;
    const int r4 = threadIdx.x >> 6;
    for (int rr = r4; rr < 64; rr += 4)
        tile[rr][c] = W[((size_t)e * F + i0 + rr) * F + o0 + c];
    __syncthreads();
    for (int rr = r4; rr < 64; rr += 4)
        WbT[(size_t)(o0 + rr) * KD + e * F + i0 + c] = f2bf(tile[c][rr]);
}

// ---------- Phase 1a: histogram of destination rows
__global__ void hist_rows(const int* __restrict__ rows, int* __restrict__ counts, int E) {
    const int e = blockIdx.x * blockDim.x + threadIdx.x;
    if (e < E) atomicAdd(&counts[rows[e]], 1);
}

// ---------- Phase 1b: exclusive scan over 65536 counts (single block)
__global__ __launch_bounds__(1024)
void scan_counts(const int* __restrict__ counts, int* __restrict__ offsets,
                 int* __restrict__ cursor) {
    __shared__ int sums[1024];
    const int t = threadIdx.x;
    const int base = t * 64;
    int s = 0;
    for (int i = 0; i < 64; ++i) s += counts[base + i];
    sums[t] = s;
    __syncthreads();
    for (int off = 1; off < 1024; off <<= 1) {
        int v = (t >= off) ? sums[t - off] : 0;
        __syncthreads();
        sums[t] += v;
        __syncthreads();
    }
    int run = (t == 0) ? 0 : sums[t - 1];
    for (int i = 0; i < 64; ++i) {
        const int c = counts[base + i];
        offsets[base + i] = run;
        cursor[base + i]  = run;
        run += c;
    }
    if (t == 1023) offsets[NN] = run;
}

// ---------- Phase 1c: scatter edges into row-sorted (col, val) pairs
__global__ void scatter_edges(const int* __restrict__ rows, const int* __restrict__ cols,
                              const float* __restrict__ vals, int* __restrict__ cursor,
                              int2* __restrict__ scv, int E) {
    const int e = blockIdx.x * blockDim.x + threadIdx.x;
    if (e >= E) return;
    const int r = rows[e];
    const int p = atomicAdd(&cursor[r], 1);
    scv[p] = make_int2(cols[e], __float_as_int(vals[e]));
}

// ---------- Phase 1d: per-row segmented gather (bf16 x), hi written f32 into d_out
__global__ __launch_bounds__(256)
void gather_rows(const short* __restrict__ xb, const int2* __restrict__ scv,
                 const int* __restrict__ offsets, float* __restrict__ hi) {
    const int lane = threadIdx.x & 63;
    int row = (blockIdx.x << 2) + (threadIdx.x >> 6);
    row = __builtin_amdgcn_readfirstlane(row);
    const int beg = offsets[row];
    const int end = offsets[row + 1];
    float4 acc = {0.f, 0.f, 0.f, 0.f};
    int j = beg;
    for (; j + 4 <= end; j += 4) {
        const int2 c0 = scv[j+0], c1 = scv[j+1], c2 = scv[j+2], c3 = scv[j+3];
        const int2 r0 = ((const int2*)(xb + (size_t)c0.x * F))[lane];
        const int2 r1 = ((const int2*)(xb + (size_t)c1.x * F))[lane];
        const int2 r2 = ((const int2*)(xb + (size_t)c2.x * F))[lane];
        const int2 r3 = ((const int2*)(xb + (size_t)c3.x * F))[lane];
        const float v0 = __int_as_float(c0.y), v1 = __int_as_float(c1.y);
        const float v2 = __int_as_float(c2.y), v3 = __int_as_float(c3.y);
        acc.x += v0*bf_lo(r0.x) + v1*bf_lo(r1.x) + v2*bf_lo(r2.x) + v3*bf_lo(r3.x);
        acc.y += v0*bf_hi(r0.x) + v1*bf_hi(r1.x) + v2*bf_hi(r2.x) + v3*bf_hi(r3.x);
        acc.z += v0*bf_lo(r0.y) + v1*bf_lo(r1.y) + v2*bf_lo(r2.y) + v3*bf_lo(r3.y);
        acc.w += v0*bf_hi(r0.y) + v1*bf_hi(r1.y) + v2*bf_hi(r2.y) + v3*bf_hi(r3.y);
    }
    for (; j < end; ++j) {
        const int2 c0 = scv[j];
        const int2 r0 = ((const int2*)(xb + (size_t)c0.x * F))[lane];
        const float v0 = __int_as_float(c0.y);
        acc.x += v0*bf_lo(r0.x); acc.y += v0*bf_hi(r0.x);
        acc.z += v0*bf_lo(r0.y); acc.w += v0*bf_hi(r0.y);
    }
    ((float4*)(hi + (size_t)row * F))[lane] = acc;
}

// ---------- Phase 2: out[n,o] = sum_e z[n,e] * (hi[n,:] @ W[e]) + x[n,o]
// A (=hi tile, 64 KB) resident in LDS for the whole kernel; B streamed through
// double-buffered LDS (2x32 KB) via global_load_lds, K-step = 64.
// B swizzle: linear LDS dest + inverse-swizzled global source + swizzled ds_read.
#define BM 128
__global__ __launch_bounds__(512, 1)
void moe_gemm(const float* __restrict__ hi, const float* __restrict__ z,
              const short* __restrict__ WbT, const float* __restrict__ x,
              float* __restrict__ out) {
    __shared__ short A_lds[BM * F];          // 64 KB, XOR-swizzled
    __shared__ short B_lds[2][256 * 64];     // 2 x 32 KB, [o][k] rows of 128 B
    __shared__ float z_lds[BM * KE];         // 4 KB
    const int tid  = threadIdx.x;
    const int lane = tid & 63;
    const int w    = tid >> 6;
    const int wr   = w >> 2;
    const int wc   = w & 3;
    const int row0 = blockIdx.x * BM;

    // --- stage B step s (expert s>>2, i0=(s&3)*64) into buf: 4 async 16B/thread
    auto stageB = [&](int s, int buf) {
        const int kb0 = s * 128;  // global k-byte base = (e*256+i0)*2
        #pragma unroll
        for (int q = 0; q < 4; ++q) {
            const int d     = (tid + q * 512) * 16;   // linear dest byte 0..32767
            const int o     = d >> 7;
            const int kbyte = d & 127;
            const char* src = (const char*)WbT + (size_t)o * (KD * 2) + kb0
                              + (kbyte ^ ((o & 7) << 4));       // inverse(=same) swizzle
            gld_lds16((char*)&B_lds[buf][0] + (w * 64 + q * 512) * 16, src);
        }
    };

    // --- prologue: z, A, B[0]
    for (int idx = tid; idx < BM * KE; idx += 512)
        z_lds[idx] = z[(size_t)row0 * KE + idx];
    stageB(0, 0);
    {
        const int m0 = tid >> 5;       // 16 rows per pass
        const int c8 = tid & 31;       // 8-float chunk
        for (int p = 0; p < BM / 16; ++p) {
            const int m = p * 16 + m0;
            const float4* src = (const float4*)(hi + (size_t)(row0 + m) * F + c8 * 8);
            const float4 a = src[0], b = src[1];
            short8 pk;
            pk[0]=f2bf(a.x); pk[1]=f2bf(a.y); pk[2]=f2bf(a.z); pk[3]=f2bf(a.w);
            pk[4]=f2bf(b.x); pk[5]=f2bf(b.y); pk[6]=f2bf(b.z); pk[7]=f2bf(b.w);
            const int idx = (m * F + c8 * 8) ^ ((m & 7) << 3);
            *(short8*)&A_lds[idx] = pk;
        }
    }
    __syncthreads();

    f32x4 acc_t[4][4], acc_e[4][4];
    #pragma unroll
    for (int mi = 0; mi < 4; ++mi)
        #pragma unroll
        for (int ni = 0; ni < 4; ++ni) {
            acc_t[mi][ni] = (f32x4){0.f, 0.f, 0.f, 0.f};
            acc_e[mi][ni] = (f32x4){0.f, 0.f, 0.f, 0.f};
        }

    const int lr    = lane & 15;
    const int krow  = 8 * (lane >> 4);
    const int rbase = (lane >> 4) * 4;

    for (int s = 0; s < 32; ++s) {
        const int cur = s & 1;
        if (s + 1 < 32) stageB(s + 1, cur ^ 1);   // prefetch next slice (async)

        const int i0 = (s & 3) * 64;
        short8 af[4][2], bf[4][2];
        #pragma unroll
        for (int ks = 0; ks < 2; ++ks) {
            #pragma unroll
            for (int mi = 0; mi < 4; ++mi) {
                const int m = wr * 64 + mi * 16 + lr;
                af[mi][ks] = *(const short8*)&A_lds[(m * F + i0 + ks * 32 + krow) ^ ((m & 7) << 3)];
            }
            #pragma unroll
            for (int ni = 0; ni < 4; ++ni) {
                const int o = wc * 64 + ni * 16 + lr;
                bf[ni][ks] = *(const short8*)&B_lds[cur][(o * 64 + ks * 32 + krow) ^ ((o & 7) << 3)];
            }
        }
        #pragma unroll
        for (int ks = 0; ks < 2; ++ks)
            #pragma unroll
            for (int mi = 0; mi < 4; ++mi)
                #pragma unroll
                for (int ni = 0; ni < 4; ++ni)
                    acc_e[mi][ni] = __builtin_amdgcn_mfma_f32_16x16x32_bf16(
                        af[mi][ks], bf[ni][ks], acc_e[mi][ni], 0, 0, 0);

        if ((s & 3) == 3) {            // expert boundary: fold z, reset acc_e
            const int e = s >> 2;
            #pragma unroll
            for (int mi = 0; mi < 4; ++mi) {
                float zv[4];
                #pragma unroll
                for (int r = 0; r < 4; ++r)
                    zv[r] = z_lds[(wr * 64 + mi * 16 + rbase + r) * KE + e];
                #pragma unroll
                for (int ni = 0; ni < 4; ++ni)
                    #pragma unroll
                    for (int r = 0; r < 4; ++r) {
                        acc_t[mi][ni][r] += zv[r] * acc_e[mi][ni][r];
                        acc_e[mi][ni][r] = 0.f;
                    }
            }
        }
        __syncthreads();               // drains vmcnt: buf[cur^1] ready, buf[cur] free
    }

    // epilogue: residual + store; ni innermost so each row's 4x64B issue back-to-back
    #pragma unroll
    for (int mi = 0; mi < 4; ++mi) {
        #pragma unroll
        for (int r = 0; r < 4; ++r) {
            const int m = wr * 64 + mi * 16 + rbase + r;
            const size_t rowoff = (size_t)(row0 + m) * F;
            #pragma unroll
            for (int ni = 0; ni < 4; ++ni) {
                const int o = wc * 64 + ni * 16 + lr;
                out[rowoff + o] = acc_t[mi][ni][r] + x[rowoff + o];
            }
        }
    }
}

extern "C" void kernel_launch(void* const* d_in, const int* in_sizes, int n_in,
                              void* d_out, int out_size, void* d_ws, size_t ws_size,
                              hipStream_t stream) {
    const float* x    = (const float*)d_in[0];
    // d_in[1] = h0 : unused by the reference (variant=False path)
    const float* z    = (const float*)d_in[2];
    const float* vals = (const float*)d_in[3];
    const float* W    = (const float*)d_in[4];
    const int* rows   = (const int*)d_in[5];
    const int* cols   = (const int*)d_in[6];
    float* out        = (float*)d_out;
    const int E = in_sizes[3];

    // workspace layout (~50 MB total)
    char* ws = (char*)d_ws;
    short* xb     = (short*)(ws);                                   // 32 MB bf16 [NN][F]
    short* WbT    = (short*)(ws + ((size_t)32 << 20));              // 1 MB
    int*   counts = (int*)  (ws + ((size_t)33 << 20));              // 256 KB
    int*   offs   = (int*)  (ws + ((size_t)33 << 20) + (256 << 10));          // 256KB+64
    int*   cursor = (int*)  (ws + ((size_t)33 << 20) + 2*(256 << 10) + 64);   // 256 KB
    int2*  scv    = (int2*) (ws + ((size_t)33 << 20) + 3*(256 << 10) + 128);  // 16 MB
    float* hi     = out;   // gather output lives in d_out; moe_gemm is in-place

    hipMemsetAsync(counts, 0, (size_t)NN * sizeof(int), stream);
    conv_x<<<(NN * F) / (256 * 8), 256, 0, stream>>>(x, xb);
    prep_w<<<dim3(4, 4, 8), 256, 0, stream>>>(W, WbT);
    hist_rows<<<(E + 255) / 256, 256, 0, stream>>>(rows, counts, E);
    scan_counts<<<1, 1024, 0, stream>>>(counts, offs, cursor);
    scatter_edges<<<(E + 255) / 256, 256, 0, stream>>>(rows, cols, vals, cursor, scv, E);
    gather_rows<<<NN / 4, 256, 0, stream>>>(xb, scv, offs, hi);
    moe_gemm<<<NN / BM, 512, 0, stream>>>(hi, z, WbT, x, out);
}

// Round 5
// 348.850 us; speedup vs baseline: 20.5272x; 1.5878x over previous
//
#include <hip/hip_runtime.h>
#include <hip/hip_bf16.h>

using short8 = __attribute__((ext_vector_type(8))) short;
using f32x4  = __attribute__((ext_vector_type(4))) float;
typedef unsigned int u32;

static constexpr int NN = 65536;   // nodes
static constexpr int F  = 256;     // feat dim
static constexpr int KE = 8;       // experts
static constexpr int KD = KE * F;  // 2048 = GEMM inner dim
static constexpr int NB = 256;     // coarse buckets (row>>8)
static constexpr int EPB = 8192;   // edges per bucket_scatter block
static constexpr int BCAP = 12288; // bucket LDS capacity (avg 8192, ~45 sigma margin)

__device__ __forceinline__ short f2bf(float f) {
    union { __hip_bfloat16 h; short s; } u;
    u.h = __float2bfloat16(f);
    return u.s;
}
__device__ __forceinline__ float bf_lo(unsigned u) { return __uint_as_float(u << 16); }
__device__ __forceinline__ float bf_hi(unsigned u) { return __uint_as_float(u & 0xFFFF0000u); }

// async 16B global->LDS (dest = wave-uniform base + lane*16, HW-enforced)
__device__ __forceinline__ void gld_lds16(void* lds, const void* g) {
    __builtin_amdgcn_global_load_lds((const __attribute__((address_space(1))) u32*)g,
                                     (__attribute__((address_space(3))) u32*)lds, 16, 0, 0);
}

// ---------- x f32 -> xb bf16 (halves gather read traffic)
__global__ __launch_bounds__(256)
void conv_x(const float* __restrict__ x, short* __restrict__ xb) {
    const size_t i = ((size_t)blockIdx.x * 256 + threadIdx.x) * 8;
    const float4 a = *(const float4*)(x + i);
    const float4 b = *(const float4*)(x + i + 4);
    short8 p;
    p[0]=f2bf(a.x); p[1]=f2bf(a.y); p[2]=f2bf(a.z); p[3]=f2bf(a.w);
    p[4]=f2bf(b.x); p[5]=f2bf(b.y); p[6]=f2bf(b.z); p[7]=f2bf(b.w);
    *(short8*)(xb + i) = p;
}

// ---------- W [8][256][256] f32 -> WbT [256][2048] bf16, WbT[o][e*256+i] = W[e][i][o]
__global__ void prep_w(const float* __restrict__ W, short* __restrict__ WbT) {
    __shared__ float tile[64][65];
    const int e  = blockIdx.z;
    const int i0 = blockIdx.x * 64;
    const int o0 = blockIdx.y * 64;
    const int c  = threadIdx.x & 63;
    const int r4 = threadIdx.x >> 6;
    for (int rr = r4; rr < 64; rr += 4)
        tile[rr][c] = W[((size_t)e * F + i0 + rr) * F + o0 + c];
    __syncthreads();
    for (int rr = r4; rr < 64; rr += 4)
        WbT[(size_t)(o0 + rr) * KD + e * F + i0 + c] = f2bf(tile[c][rr]);
}

// ---------- P1: coarse-bucket histogram (256 buckets of 256 rows)
__global__ __launch_bounds__(256)
void bucket_hist(const int* __restrict__ rows, int* __restrict__ bcount, int E) {
    __shared__ int h[NB];
    const int tid = threadIdx.x;
    h[tid] = 0;
    __syncthreads();
    const int base = blockIdx.x * EPB;
    const int lim  = min(EPB, E - base);
    for (int i = tid; i < lim; i += 256)
        atomicAdd(&h[rows[base + i] >> 8], 1);
    __syncthreads();
    if (h[tid]) atomicAdd(&bcount[tid], h[tid]);
}

// ---------- P2: 256-wide exclusive scan -> bucket bases + cursors
__global__ __launch_bounds__(256)
void bucket_scan(const int* __restrict__ bcount, int* __restrict__ bbase,
                 int* __restrict__ bcursor) {
    __shared__ int s[NB];
    const int tid = threadIdx.x;
    const int c = bcount[tid];
    s[tid] = c;
    __syncthreads();
    for (int off = 1; off < NB; off <<= 1) {
        int v = (tid >= off) ? s[tid - off] : 0;
        __syncthreads();
        s[tid] += v;
        __syncthreads();
    }
    const int excl = s[tid] - c;
    bbase[tid]   = excl;
    bcursor[tid] = excl;
    if (tid == NB - 1) bbase[NB] = s[tid];
}

// ---------- P3: scatter edges into coarse buckets.
// Per block: LDS hist -> one global cursor atomic per non-empty bucket reserves a
// contiguous run -> LDS-ranked writes. Active write window per block ~64 KB
// (256 runs x ~256 B) on one XCD -> L2 merges to full lines.
__global__ __launch_bounds__(256)
void bucket_scatter(const int* __restrict__ rows, const int* __restrict__ cols,
                    const float* __restrict__ vals, int* __restrict__ bcursor,
                    int2* __restrict__ tmp, int E) {
    __shared__ int h[NB], wb[NB];
    const int tid = threadIdx.x;
    h[tid] = 0;
    __syncthreads();
    const int base = blockIdx.x * EPB;
    const int lim  = min(EPB, E - base);
    for (int i = tid; i < lim; i += 256)
        atomicAdd(&h[rows[base + i] >> 8], 1);
    __syncthreads();
    const int c = h[tid];
    wb[tid] = c ? atomicAdd(&bcursor[tid], c) : 0;
    h[tid] = 0;
    __syncthreads();
    for (int i = tid; i < lim; i += 256) {
        const int r  = rows[base + i];
        const int bk = r >> 8;
        const int rank = atomicAdd(&h[bk], 1);
        tmp[wb[bk] + rank] = make_int2(((r & 255) << 16) | cols[base + i],
                                       __float_as_int(vals[base + i]));
    }
}

// ---------- P4: one block per bucket: exact-row sort (in place) + row offsets.
// Bucket loaded into LDS so the in-place global rewrite is hazard-free.
__global__ __launch_bounds__(256)
void bucket_to_csr(const int* __restrict__ bbase, int2* __restrict__ tmp,
                   int* __restrict__ offsets) {
    __shared__ int2 buf[BCAP];          // 96 KB
    __shared__ int h[NB], off[NB];
    const int tid = threadIdx.x;
    const int k   = blockIdx.x;
    const int beg = bbase[k];
    const int end = bbase[k + 1];
    const int n   = end - beg;
    h[tid] = 0;
    __syncthreads();
    for (int i = tid; i < n; i += 256) {
        const int2 e = tmp[beg + i];
        if (i < BCAP) buf[i] = e;
        atomicAdd(&h[e.x >> 16], 1);
    }
    __syncthreads();
    const int c = h[tid];
    off[tid] = c;
    __syncthreads();
    for (int o = 1; o < NB; o <<= 1) {
        int v = (tid >= o) ? off[tid - o] : 0;
        __syncthreads();
        off[tid] += v;
        __syncthreads();
    }
    const int excl = off[tid] - c;
    offsets[k * NB + tid] = beg + excl;
    if (k == NB - 1 && tid == NB - 1) offsets[NN] = end;
    h[tid] = excl;                      // reuse as within-bucket cursor
    __syncthreads();
    for (int i = tid; i < n; i += 256) {
        const int2 e = (i < BCAP) ? buf[i] : tmp[beg + i];
        const int r = e.x >> 16;
        const int pos = atomicAdd(&h[r], 1);
        tmp[beg + pos] = make_int2(e.x & 0xFFFF, e.y);
    }
}

// ---------- gather: per-row segmented accumulate (bf16 x), hi written f32 into d_out
__global__ __launch_bounds__(256)
void gather_rows(const short* __restrict__ xb, const int2* __restrict__ scv,
                 const int* __restrict__ offsets, float* __restrict__ hi) {
    const int lane = threadIdx.x & 63;
    int row = (blockIdx.x << 2) + (threadIdx.x >> 6);
    row = __builtin_amdgcn_readfirstlane(row);
    const int beg = offsets[row];
    const int end = offsets[row + 1];
    float4 acc = {0.f, 0.f, 0.f, 0.f};
    int j = beg;
    for (; j + 4 <= end; j += 4) {
        const int2 c0 = scv[j+0], c1 = scv[j+1], c2 = scv[j+2], c3 = scv[j+3];
        const int2 r0 = ((const int2*)(xb + (size_t)c0.x * F))[lane];
        const int2 r1 = ((const int2*)(xb + (size_t)c1.x * F))[lane];
        const int2 r2 = ((const int2*)(xb + (size_t)c2.x * F))[lane];
        const int2 r3 = ((const int2*)(xb + (size_t)c3.x * F))[lane];
        const float v0 = __int_as_float(c0.y), v1 = __int_as_float(c1.y);
        const float v2 = __int_as_float(c2.y), v3 = __int_as_float(c3.y);
        acc.x += v0*bf_lo(r0.x) + v1*bf_lo(r1.x) + v2*bf_lo(r2.x) + v3*bf_lo(r3.x);
        acc.y += v0*bf_hi(r0.x) + v1*bf_hi(r1.x) + v2*bf_hi(r2.x) + v3*bf_hi(r3.x);
        acc.z += v0*bf_lo(r0.y) + v1*bf_lo(r1.y) + v2*bf_lo(r2.y) + v3*bf_lo(r3.y);
        acc.w += v0*bf_hi(r0.y) + v1*bf_hi(r1.y) + v2*bf_hi(r2.y) + v3*bf_hi(r3.y);
    }
    for (; j < end; ++j) {
        const int2 c0 = scv[j];
        const int2 r0 = ((const int2*)(xb + (size_t)c0.x * F))[lane];
        const float v0 = __int_as_float(c0.y);
        acc.x += v0*bf_lo(r0.x); acc.y += v0*bf_hi(r0.x);
        acc.z += v0*bf_lo(r0.y); acc.w += v0*bf_hi(r0.y);
    }
    ((float4*)(hi + (size_t)row * F))[lane] = acc;
}

// ---------- GEMM: out[n,o] = sum_e z[n,e] * (hi[n,:] @ W[e]) + x[n,o]
// A resident in LDS; B double-buffered via global_load_lds, K-step 64.
#define BM 128
__global__ __launch_bounds__(512, 1)
void moe_gemm(const float* __restrict__ hi, const float* __restrict__ z,
              const short* __restrict__ WbT, const float* __restrict__ x,
              float* __restrict__ out) {
    __shared__ short A_lds[BM * F];          // 64 KB, XOR-swizzled
    __shared__ short B_lds[2][256 * 64];     // 2 x 32 KB
    __shared__ float z_lds[BM * KE];         // 4 KB
    const int tid  = threadIdx.x;
    const int lane = tid & 63;
    const int w    = tid >> 6;
    const int wr   = w >> 2;
    const int wc   = w & 3;
    const int row0 = blockIdx.x * BM;

    auto stageB = [&](int s, int buf) {
        const int kb0 = s * 128;
        #pragma unroll
        for (int q = 0; q < 4; ++q) {
            const int d     = (tid + q * 512) * 16;
            const int o     = d >> 7;
            const int kbyte = d & 127;
            const char* src = (const char*)WbT + (size_t)o * (KD * 2) + kb0
                              + (kbyte ^ ((o & 7) << 4));
            gld_lds16((char*)&B_lds[buf][0] + (w * 64 + q * 512) * 16, src);
        }
    };

    for (int idx = tid; idx < BM * KE; idx += 512)
        z_lds[idx] = z[(size_t)row0 * KE + idx];
    stageB(0, 0);
    {
        const int m0 = tid >> 5;
        const int c8 = tid & 31;
        for (int p = 0; p < BM / 16; ++p) {
            const int m = p * 16 + m0;
            const float4* src = (const float4*)(hi + (size_t)(row0 + m) * F + c8 * 8);
            const float4 a = src[0], b = src[1];
            short8 pk;
            pk[0]=f2bf(a.x); pk[1]=f2bf(a.y); pk[2]=f2bf(a.z); pk[3]=f2bf(a.w);
            pk[4]=f2bf(b.x); pk[5]=f2bf(b.y); pk[6]=f2bf(b.z); pk[7]=f2bf(b.w);
            const int idx = (m * F + c8 * 8) ^ ((m & 7) << 3);
            *(short8*)&A_lds[idx] = pk;
        }
    }
    __syncthreads();

    f32x4 acc_t[4][4], acc_e[4][4];
    #pragma unroll
    for (int mi = 0; mi < 4; ++mi)
        #pragma unroll
        for (int ni = 0; ni < 4; ++ni) {
            acc_t[mi][ni] = (f32x4){0.f, 0.f, 0.f, 0.f};
            acc_e[mi][ni] = (f32x4){0.f, 0.f, 0.f, 0.f};
        }

    const int lr    = lane & 15;
    const int krow  = 8 * (lane >> 4);
    const int rbase = (lane >> 4) * 4;

    for (int s = 0; s < 32; ++s) {
        const int cur = s & 1;
        if (s + 1 < 32) stageB(s + 1, cur ^ 1);

        const int i0 = (s & 3) * 64;
        short8 af[4][2], bf[4][2];
        #pragma unroll
        for (int ks = 0; ks < 2; ++ks) {
            #pragma unroll
            for (int mi = 0; mi < 4; ++mi) {
                const int m = wr * 64 + mi * 16 + lr;
                af[mi][ks] = *(const short8*)&A_lds[(m * F + i0 + ks * 32 + krow) ^ ((m & 7) << 3)];
            }
            #pragma unroll
            for (int ni = 0; ni < 4; ++ni) {
                const int o = wc * 64 + ni * 16 + lr;
                bf[ni][ks] = *(const short8*)&B_lds[cur][(o * 64 + ks * 32 + krow) ^ ((o & 7) << 3)];
            }
        }
        #pragma unroll
        for (int ks = 0; ks < 2; ++ks)
            #pragma unroll
            for (int mi = 0; mi < 4; ++mi)
                #pragma unroll
                for (int ni = 0; ni < 4; ++ni)
                    acc_e[mi][ni] = __builtin_amdgcn_mfma_f32_16x16x32_bf16(
                        af[mi][ks], bf[ni][ks], acc_e[mi][ni], 0, 0, 0);

        if ((s & 3) == 3) {
            const int e = s >> 2;
            #pragma unroll
            for (int mi = 0; mi < 4; ++mi) {
                float zv[4];
                #pragma unroll
                for (int r = 0; r < 4; ++r)
                    zv[r] = z_lds[(wr * 64 + mi * 16 + rbase + r) * KE + e];
                #pragma unroll
                for (int ni = 0; ni < 4; ++ni)
                    #pragma unroll
                    for (int r = 0; r < 4; ++r) {
                        acc_t[mi][ni][r] += zv[r] * acc_e[mi][ni][r];
                        acc_e[mi][ni][r] = 0.f;
                    }
            }
        }
        __syncthreads();
    }

    #pragma unroll
    for (int mi = 0; mi < 4; ++mi) {
        #pragma unroll
        for (int r = 0; r < 4; ++r) {
            const int m = wr * 64 + mi * 16 + rbase + r;
            const size_t rowoff = (size_t)(row0 + m) * F;
            #pragma unroll
            for (int ni = 0; ni < 4; ++ni) {
                const int o = wc * 64 + ni * 16 + lr;
                out[rowoff + o] = acc_t[mi][ni][r] + x[rowoff + o];
            }
        }
    }
}

extern "C" void kernel_launch(void* const* d_in, const int* in_sizes, int n_in,
                              void* d_out, int out_size, void* d_ws, size_t ws_size,
                              hipStream_t stream) {
    const float* x    = (const float*)d_in[0];
    // d_in[1] = h0 : unused by the reference (variant=False path)
    const float* z    = (const float*)d_in[2];
    const float* vals = (const float*)d_in[3];
    const float* W    = (const float*)d_in[4];
    const int* rows   = (const int*)d_in[5];
    const int* cols   = (const int*)d_in[6];
    float* out        = (float*)d_out;
    const int E = in_sizes[3];

    // workspace layout (~50 MB total)
    char* ws = (char*)d_ws;
    short* xb      = (short*)(ws);                               // 32 MB bf16 [NN][F]
    short* WbT     = (short*)(ws + ((size_t)32 << 20));          // 1 MB
    int*   offsets = (int*)  (ws + ((size_t)33 << 20));          // 256 KB + 4
    int*   bcount  = (int*)  (ws + ((size_t)33 << 20) + 264*1024);
    int*   bbase   = (int*)  (ws + ((size_t)33 << 20) + 266*1024);
    int*   bcursor = (int*)  (ws + ((size_t)33 << 20) + 268*1024);
    int2*  tmp     = (int2*) (ws + ((size_t)34 << 20));          // 16 MB
    float* hi      = out;    // gather output lives in d_out; moe_gemm is in-place

    const int nblk = (E + EPB - 1) / EPB;
    hipMemsetAsync(bcount, 0, NB * sizeof(int), stream);
    conv_x<<<(NN * F) / (256 * 8), 256, 0, stream>>>(x, xb);
    prep_w<<<dim3(4, 4, 8), 256, 0, stream>>>(W, WbT);
    bucket_hist<<<nblk, 256, 0, stream>>>(rows, bcount, E);
    bucket_scan<<<1, 256, 0, stream>>>(bcount, bbase, bcursor);
    bucket_scatter<<<nblk, 256, 0, stream>>>(rows, cols, vals, bcursor, tmp, E);
    bucket_to_csr<<<NB, 256, 0, stream>>>(bbase, tmp, offsets);
    gather_rows<<<NN / 4, 256, 0, stream>>>(xb, tmp, offsets, hi);
    moe_gemm<<<NN / BM, 512, 0, stream>>>(hi, z, WbT, x, out);
}